// Round 3
// baseline (14000.081 us; speedup 1.0000x reference)
//
#include <hip/hip_runtime.h>
#include <hip/hip_bf16.h>

// nondecayRNN: B=256, T=512, I=128, H=1024, O=128
//   hiddens[b,t,:] = relu(x[b,t,:]@W_in^T + b_in + h_{t-1}@Wrec^T)
//   outs[b,t,:]    = softmax(hiddens[b,t,:]@W_out^T + b_out)
//
// k_rnn: persistent kernel, 256 WGs x 256 thr (PLAIN launch — cooperative
//   launch is not graph-capturable and silently no-ops in the harness).
//   16 groups (16 batch rows each) x 16 WGs (64-wide H slice each).
//   Wrec slice lives in VGPRs as bf16 mfma fragments. Split-K over 4 waves,
//   LDS reduce. Cross-WG h exchange: agent-scope atomics + per-step counter.
//   No grid barrier needed: sync is per-group counters only; 256 WGs x 4
//   waves over 256 CUs (capacity 8/CU) are always co-resident.
// k_out: parallel output GEMM + softmax.

typedef __attribute__((ext_vector_type(8))) short short8;
typedef __attribute__((ext_vector_type(4))) float f32x4;
typedef __attribute__((ext_vector_type(4))) unsigned short ushort4_t;

#define SCOPE_AGENT __HIP_MEMORY_SCOPE_AGENT

__device__ __forceinline__ unsigned short f2bf(float f) {
  union { float f; unsigned u; } c; c.f = f;
  unsigned r = c.u + 0x7fffu + ((c.u >> 16) & 1u);   // RNE
  return (unsigned short)(r >> 16);
}

// ---------------------------------------------------------------- k_rnn ----
__global__ __launch_bounds__(256, 1) void k_rnn(
    const float* __restrict__ x,     // [256][512][128]
    const float* __restrict__ W_in,  // [1024][128]
    const float* __restrict__ b_in,  // [1024]
    const float* __restrict__ Wrec,  // [1024][1024]
    float* __restrict__ hid,         // d_out part0: [256][512][1024]
    unsigned short* __restrict__ hbuf, // [2][16 groups][16 rows][1024] bf16
    unsigned int* __restrict__ ctr)    // [16 groups][512]
{
  const int wg  = blockIdx.x;   // 0..255
  const int g   = wg >> 4;      // batch group 0..15
  const int w   = wg & 15;      // H-slice 0..15 (j in [w*64, w*64+64))
  const int tid = threadIdx.x;
  const int wv  = tid >> 6;     // wave 0..3 (k-range [wv*256, +256))
  const int lane = tid & 63;
  const int l15 = lane & 15;
  const int lhi = lane >> 4;    // 0..3

  __shared__ float part[4][4][4][64];  // [wave][jt][reg][lane] = 16 KB

  // ---- prologue: Wrec slice -> register fragments (bf16) ----
  // wb[jt][kc]: B-frag for j-tile jt (16 j's), k chunk kc (32 k's of my wave range)
  short8 wb[4][8];
#pragma unroll
  for (int jt = 0; jt < 4; ++jt) {
#pragma unroll
    for (int kc = 0; kc < 8; ++kc) {
      const float* p = Wrec + (size_t)(w*64 + jt*16 + l15) * 1024 + wv*256 + kc*32 + lhi*8;
      short8 s;
#pragma unroll
      for (int i = 0; i < 8; ++i) s[i] = (short)f2bf(p[i]);
      wb[jt][kc] = s;
    }
  }
  // W_in fragments: xin split-K over waves, wave wv covers i in [wv*32, +32)
  short8 wi[4];
#pragma unroll
  for (int jt = 0; jt < 4; ++jt) {
    const float* p = W_in + (size_t)(w*64 + jt*16 + l15) * 128 + wv*32 + lhi*8;
    short8 s;
#pragma unroll
    for (int i = 0; i < 8; ++i) s[i] = (short)f2bf(p[i]);
    wi[jt] = s;
  }
  const float bin = b_in[w*64 + wv*16 + l15];  // for reduce phase (jt = wv)

  // ---- time loop ----
  for (int t = 0; t < 512; ++t) {
    f32x4 acc[4];
#pragma unroll
    for (int jt = 0; jt < 4; ++jt) acc[jt] = (f32x4){0.f, 0.f, 0.f, 0.f};

    // xin contribution (independent of the flag wait -> issue first)
    {
      const float* xp = x + (size_t)(g*16 + l15) * (512*128) + t*128 + wv*32 + lhi*8;
      short8 a;
#pragma unroll
      for (int i = 0; i < 8; ++i) a[i] = (short)f2bf(xp[i]);
#pragma unroll
      for (int jt = 0; jt < 4; ++jt)
        acc[jt] = __builtin_amdgcn_mfma_f32_16x16x32_bf16(a, wi[jt], acc[jt], 0, 0, 0);
    }

    if (t > 0) {
      // wait for all 16 WGs of my group to have published h_{t-1}
      while (__hip_atomic_load(&ctr[g*512 + (t-1)], __ATOMIC_ACQUIRE, SCOPE_AGENT) < 16u)
        __builtin_amdgcn_s_sleep(1);
      // A-frags straight from hbuf via coherent loads
      const unsigned long long* hp = (const unsigned long long*)
          (hbuf + (size_t)(((t-1) & 1) * 16 + g) * 16384 + l15*1024 + wv*256);
#pragma unroll
      for (int kc = 0; kc < 8; ++kc) {
        unsigned long long u0 = __hip_atomic_load(hp + kc*8 + lhi*2,     __ATOMIC_RELAXED, SCOPE_AGENT);
        unsigned long long u1 = __hip_atomic_load(hp + kc*8 + lhi*2 + 1, __ATOMIC_RELAXED, SCOPE_AGENT);
        union { unsigned long long q[2]; short8 v; } cv;
        cv.q[0] = u0; cv.q[1] = u1;
#pragma unroll
        for (int jt = 0; jt < 4; ++jt)
          acc[jt] = __builtin_amdgcn_mfma_f32_16x16x32_bf16(cv.v, wb[jt][kc], acc[jt], 0, 0, 0);
      }
    }

    // cross-wave split-K reduce via LDS
#pragma unroll
    for (int jt = 0; jt < 4; ++jt)
#pragma unroll
      for (int r = 0; r < 4; ++r) part[wv][jt][r][lane] = acc[jt][r];
    __syncthreads();

    float v[4];
#pragma unroll
    for (int r = 0; r < 4; ++r) {
      float s = part[0][wv][r][lane] + part[1][wv][r][lane]
              + part[2][wv][r][lane] + part[3][wv][r][lane] + bin;
      v[r] = fmaxf(s, 0.0f);
    }

    // publish h_t (bf16, coherent) + write hiddens (f32, plain)
    unsigned short* hw = hbuf + (size_t)((t & 1) * 16 + g) * 16384;
    const int j = w*64 + wv*16 + l15;
#pragma unroll
    for (int r = 0; r < 4; ++r) {
      const int row = lhi*4 + r;  // C/D mapping: row=(lane>>4)*4+reg, col=lane&15
      __hip_atomic_store(&hw[row*1024 + j], f2bf(v[r]), __ATOMIC_RELAXED, SCOPE_AGENT);
      hid[((size_t)(g*16 + row) * 512 + t) * 1024 + j] = v[r];
    }
    __syncthreads();  // drains vmcnt(0) for all waves' stores + LDS WAR
    if (tid == 0)
      __hip_atomic_fetch_add(&ctr[g*512 + t], 1u, __ATOMIC_RELEASE, SCOPE_AGENT);
  }
}

// ---------------------------------------------------------------- k_prep ---
__global__ void k_prep(const float* __restrict__ W_out, unsigned short* __restrict__ wob) {
  const int i = (blockIdx.x * 256 + threadIdx.x) * 8;  // 128*1024 elements
  float4 a = *(const float4*)(W_out + i);
  float4 b = *(const float4*)(W_out + i + 4);
  short8 s;
  s[0] = (short)f2bf(a.x); s[1] = (short)f2bf(a.y);
  s[2] = (short)f2bf(a.z); s[3] = (short)f2bf(a.w);
  s[4] = (short)f2bf(b.x); s[5] = (short)f2bf(b.y);
  s[6] = (short)f2bf(b.z); s[7] = (short)f2bf(b.w);
  *(short8*)(wob + i) = s;
}

// ---------------------------------------------------------------- k_out ----
__global__ __launch_bounds__(256, 1) void k_out(
    const float* __restrict__ hid,          // [131072][1024] f32
    const unsigned short* __restrict__ wob, // [128][1024] bf16
    const float* __restrict__ b_out,        // [128]
    float* __restrict__ outp)               // [131072][128] f32
{
  __shared__ unsigned short hlds[32 * 1024];  // 64 KB, XOR-swizzled rows
  const int bt0 = blockIdx.x * 32;
  const int tid = threadIdx.x;
  const int wv = tid >> 6, lane = tid & 63, l15 = lane & 15, lhi = lane >> 4;
  const int mh = wv >> 1, nh = wv & 1;

  // stage hiddens tile [32][1024] f32 -> bf16 in LDS
#pragma unroll 4
  for (int i = 0; i < 32; ++i) {
    const float4 hv = *(const float4*)(hid + (size_t)(bt0 + i) * 1024 + tid * 4);
    ushort4_t s4;
    s4.x = f2bf(hv.x); s4.y = f2bf(hv.y); s4.z = f2bf(hv.z); s4.w = f2bf(hv.w);
    unsigned byte = (unsigned)(i * 2048 + tid * 8) ^ (unsigned)((i & 7) << 4);
    *(ushort4_t*)((char*)hlds + byte) = s4;
  }
  __syncthreads();

  f32x4 acc[4];
#pragma unroll
  for (int jt = 0; jt < 4; ++jt) acc[jt] = (f32x4){0.f, 0.f, 0.f, 0.f};

#pragma unroll 4
  for (int kc = 0; kc < 32; ++kc) {
    const int row = mh*16 + l15;
    unsigned byte = (unsigned)(row * 2048 + kc * 64 + lhi * 16) ^ (unsigned)((row & 7) << 4);
    short8 a = *(const short8*)((const char*)hlds + byte);
#pragma unroll
    for (int jt = 0; jt < 4; ++jt) {
      short8 b = *(const short8*)(wob + (size_t)(nh*64 + jt*16 + l15) * 1024 + kc*32 + lhi*8);
      acc[jt] = __builtin_amdgcn_mfma_f32_16x16x32_bf16(a, b, acc[jt], 0, 0, 0);
    }
  }
  __syncthreads();  // done reading hlds; reuse as logits [32][128] f32

  float* lg = (float*)hlds;
#pragma unroll
  for (int jt = 0; jt < 4; ++jt) {
    const int col = nh*64 + jt*16 + l15;
    const float bo = b_out[col];
#pragma unroll
    for (int r = 0; r < 4; ++r) {
      const int row = mh*16 + lhi*4 + r;
      lg[row * 128 + col] = acc[jt][r] + bo;
    }
  }
  __syncthreads();

  // softmax: 8 threads per row, 16 cols each
  const int row = tid >> 3, sub = tid & 7;
  float vvv[16];
#pragma unroll
  for (int q = 0; q < 4; ++q) {
    f32x4 t4 = *(const f32x4*)(lg + row * 128 + sub * 16 + q * 4);
    vvv[q*4+0] = t4[0]; vvv[q*4+1] = t4[1]; vvv[q*4+2] = t4[2]; vvv[q*4+3] = t4[3];
  }
  float m = vvv[0];
#pragma unroll
  for (int i = 1; i < 16; ++i) m = fmaxf(m, vvv[i]);
  for (int off = 1; off < 8; off <<= 1) m = fmaxf(m, __shfl_xor(m, off, 64));
  float s = 0.f;
#pragma unroll
  for (int i = 0; i < 16; ++i) { vvv[i] = __expf(vvv[i] - m); s += vvv[i]; }
  for (int off = 1; off < 8; off <<= 1) s += __shfl_xor(s, off, 64);
  const float inv = 1.0f / s;
  float* op = outp + (size_t)(bt0 + row) * 128 + sub * 16;
#pragma unroll
  for (int q = 0; q < 4; ++q) {
    f32x4 o;
    o[0] = vvv[q*4+0]*inv; o[1] = vvv[q*4+1]*inv; o[2] = vvv[q*4+2]*inv; o[3] = vvv[q*4+3]*inv;
    *(f32x4*)(op + q * 4) = o;
  }
}

// ------------------------------------------------------------- launcher ----
extern "C" void kernel_launch(void* const* d_in, const int* in_sizes, int n_in,
                              void* d_out, int out_size, void* d_ws, size_t ws_size,
                              hipStream_t stream) {
  const float* x     = (const float*)d_in[0];
  const float* W_in  = (const float*)d_in[1];
  const float* b_in  = (const float*)d_in[2];
  const float* Wrec  = (const float*)d_in[3];
  const float* W_out = (const float*)d_in[4];
  const float* b_out = (const float*)d_in[5];

  float* hid  = (float*)d_out;                               // [256][512][1024]
  float* outp = (float*)d_out + (size_t)256 * 512 * 1024;    // [256][512][128]

  char* ws = (char*)d_ws;
  unsigned short* hbuf = (unsigned short*)ws;                         // 1 MB
  unsigned int*  ctr   = (unsigned int*)(ws + (1 << 20));             // 32 KB
  unsigned short* wob  = (unsigned short*)(ws + (1 << 20) + (32 << 10)); // 256 KB

  hipMemsetAsync(ctr, 0, 16 * 512 * sizeof(unsigned int), stream);
  k_prep<<<64, 256, 0, stream>>>(W_out, wob);

  // Plain launch (NOT hipLaunchCooperativeKernel — not graph-capturable).
  // Sync inside k_rnn is per-group atomic counters only; 256 small WGs are
  // always co-resident on 256 CUs.
  k_rnn<<<dim3(256), dim3(256), 0, stream>>>(x, W_in, b_in, Wrec, hid, hbuf, ctr);

  k_out<<<4096, 256, 0, stream>>>(hid, wob, b_out, outp);
}